// Round 2
// baseline (537.362 us; speedup 1.0000x reference)
//
#include <hip/hip_runtime.h>

// Problem constants (fixed shapes from reference setup_inputs)
#define N_INST 32768
#define DIM    2048
#define DP     512
#define NCLS   4

typedef _Float16 half8_t  __attribute__((ext_vector_type(8)));
typedef float    float4_t __attribute__((ext_vector_type(4)));

// Workspace layout (bytes). Total ~2.3 MB.
#define OFF_UHI   0ull                              // DP*DIM fp16 = 2 MB
#define OFF_S     (OFF_UHI  + (size_t)DP*DIM*2)     // N fp32 = 128 KB
#define OFF_STAT  (OFF_S    + (size_t)N_INST*4)     // 2 fp32
#define OFF_PSTAT (OFF_STAT + 256ull)               // 32*2 fp32 partial stats
#define OFF_T     (OFF_PSTAT+ 256ull)               // DIM fp32 pooled vector

__device__ __forceinline__ float tanh_fast(float x) {
  // tanh(x) = 1 - 2/(exp(2x)+1); exp overflow->inf gives exact +/-1 limits
  float e = __expf(2.0f * x);
  return 1.0f - 2.0f / (e + 1.0f);
}

// async global->LDS, 16B per lane. LDS dest is wave-uniform base + lane*16.
typedef const unsigned int __attribute__((address_space(1)))* gas_t;
typedef unsigned int       __attribute__((address_space(3)))* las_t;
__device__ __forceinline__ void gl16(const void* g, void* l) {
  __builtin_amdgcn_global_load_lds((gas_t)g, (las_t)l, 16, 0, 0);
}

// ---- fp32 -> fp16 convert (U only; 8 elems/thread) ----
__global__ __launch_bounds__(256) void k_cvt(const float4* __restrict__ in,
                                             half8_t* __restrict__ out) {
  int i = blockIdx.x * 256 + threadIdx.x;
  float4 a = in[2 * i], b = in[2 * i + 1];
  half8_t h;
  h[0] = (_Float16)a.x; h[1] = (_Float16)a.y;
  h[2] = (_Float16)a.z; h[3] = (_Float16)a.w;
  h[4] = (_Float16)b.x; h[5] = (_Float16)b.y;
  h[6] = (_Float16)b.z; h[7] = (_Float16)b.w;
  out[i] = h;
}

// ---- fused score GEMM, m97-structure:
// s[n] = sum_j Wmta[j]*tanh( Uhi[j,:] . V[n,:] )
// 128x128 tile, BK=32, 4 waves (2x2), wave tile 64x64 = 4x4 MFMA 16x16x32 f16.
// Both operands staged global->LDS via global_load_lds_dwordx4 (no VGPR
// round-trip, no staging VALU). B (V) stays fp32 in LDS; fp16 conversion
// happens at fragment-read time via v_cvt_pkrtz (2 floats/instr).
//
// Bank-conflict fix (was 8-way on all frag reads): XOR swizzle of the 16B
// slot index within each LDS row, folded into the per-lane GLOBAL source
// address (LDS dest of global_load_lds must stay linear). Readers apply the
// same XOR. A (64B rows, 4 slots): slot ^= (row>>1)&3. B (128B rows, 8
// slots): slot ^= row&7. Both reduce frag reads to 2-way (free per m136).
__global__ __launch_bounds__(256) void k_score_gemm(
    const _Float16* __restrict__ Uhi, const float* __restrict__ V,
    const float* __restrict__ Wmta, float* __restrict__ s) {
  __shared__ _Float16 lA[128 * 32];   // 8 KB  (fp16, row stride 64 B)
  __shared__ float    lB[128 * 32];   // 16 KB (fp32, row stride 128 B)

  const int tid  = threadIdx.x;
  const int lane = tid & 63;
  const int wv   = tid >> 6;        // 0..3
  const int waveM = wv >> 1;        // 0..1
  const int waveN = wv & 1;         // 0..1
  const int quad = lane >> 4;       // 0..3
  const int col  = lane & 15;

  // XCD-aware swizzle: 4 mb-siblings of one nb sit 8 apart in blockIdx
  // (same XCD under %8 round-robin), so a V tile is fetched ~once per XCD.
  const int b   = blockIdx.x;
  const int grp = b >> 5;
  const int win = b & 31;
  const int mb  = win >> 3;             // 0..3
  const int nb  = grp * 8 + (win & 7);  // 0..255

  const int aRow0  = mb * 128;
  const int bRow0  = nb * 128;
  const int kStart = (nb & 63) << 5;    // K-phase stagger (decorrelates L2/HBM)

  // ---- staging source addresses (swizzle pre-applied) ----
  // A: 8 chunks x 1024B; chunk ch = wv*2+{0,1}; lane l -> row ch*16 + (l>>2),
  //    physical slot l&3 sources logical slot (l&3)^((row>>1)&3).
  const int rA0 = wv * 32 + (lane >> 2);      // rows wv*32 .. +15
  const int sA  = (lane & 3) ^ ((rA0 >> 1) & 3);   // same for row+16
  const _Float16* gA0 = Uhi + (size_t)(aRow0 + rA0) * DIM + sA * 8;
  const _Float16* gA1 = gA0 + (size_t)16 * DIM;
  _Float16* lAd0 = &lA[(wv * 2 + 0) * 512];   // wave-uniform dests
  _Float16* lAd1 = &lA[(wv * 2 + 1) * 512];

  // B: 16 chunks x 1024B; chunk ch = wv*4+j; lane l -> row ch*8 + (l>>3),
  //    physical slot l&7 sources logical slot (l&7)^(row&7).
  const int rB0 = wv * 32 + (lane >> 3);      // rows wv*32 .. +7
  const int sB  = (lane & 7) ^ (rB0 & 7);     // row&7 invariant under +8
  const float* gB0 = V + (size_t)(bRow0 + rB0) * DIM + sB * 4;
  const float* gB1 = gB0 + (size_t)8  * DIM;
  const float* gB2 = gB0 + (size_t)16 * DIM;
  const float* gB3 = gB0 + (size_t)24 * DIM;
  float* lBd0 = &lB[(wv * 4 + 0) * 256];
  float* lBd1 = &lB[(wv * 4 + 1) * 256];
  float* lBd2 = &lB[(wv * 4 + 2) * 256];
  float* lBd3 = &lB[(wv * 4 + 3) * 256];

  // ---- fragment-read byte offsets (precomputed, constant across K-loop) ----
  int offA[4];
#pragma unroll
  for (int mi = 0; mi < 4; ++mi) {
    const int r = waveM * 64 + mi * 16 + col;
    offA[mi] = r * 64 + ((quad ^ ((r >> 1) & 3)) << 4);
  }
  int offB[4];   // second 16B of the pair is offB ^ 16 (slot^1)
#pragma unroll
  for (int ni = 0; ni < 4; ++ni) {
    const int r = waveN * 64 + ni * 16 + col;
    offB[ni] = r * 128 + ((((quad << 1)) ^ (r & 7)) << 4);
  }

  float4_t acc[4][4];
  const float4_t z4 = {0.f, 0.f, 0.f, 0.f};
#pragma unroll
  for (int i = 0; i < 4; i++)
#pragma unroll
    for (int j = 0; j < 4; j++) acc[i][j] = z4;

  const char* lAc = (const char*)lA;
  const char* lBc = (const char*)lB;

  for (int ki = 0; ki < 64; ++ki) {
    const int k = (kStart + (ki << 5)) & (DIM - 1);
    __syncthreads();          // previous iter's frag reads done before overwrite
    gl16(gA0 + k, lAd0);
    gl16(gA1 + k, lAd1);
    gl16(gB0 + k, lBd0);
    gl16(gB1 + k, lBd1);
    gl16(gB2 + k, lBd2);
    gl16(gB3 + k, lBd3);
    __syncthreads();          // compiler drains vmcnt(0) -> tile resident

    half8_t af[4];
#pragma unroll
    for (int mi = 0; mi < 4; ++mi)
      af[mi] = *(const half8_t*)(lAc + offA[mi]);

#pragma unroll
    for (int ni = 0; ni < 4; ++ni) {
      const float4_t x = *(const float4_t*)(lBc + offB[ni]);
      const float4_t y = *(const float4_t*)(lBc + (offB[ni] ^ 16));
      const auto c0 = __builtin_amdgcn_cvt_pkrtz(x[0], x[1]);  // __fp16 x2
      const auto c1 = __builtin_amdgcn_cvt_pkrtz(x[2], x[3]);
      const auto c2 = __builtin_amdgcn_cvt_pkrtz(y[0], y[1]);
      const auto c3 = __builtin_amdgcn_cvt_pkrtz(y[2], y[3]);
      half8_t bf;
      bf[0] = (_Float16)c0[0]; bf[1] = (_Float16)c0[1];
      bf[2] = (_Float16)c1[0]; bf[3] = (_Float16)c1[1];
      bf[4] = (_Float16)c2[0]; bf[5] = (_Float16)c2[1];
      bf[6] = (_Float16)c3[0]; bf[7] = (_Float16)c3[1];
#pragma unroll
      for (int mi = 0; mi < 4; ++mi)
        acc[mi][ni] = __builtin_amdgcn_mfma_f32_16x16x32_f16(af[mi], bf, acc[mi][ni], 0, 0, 0);
    }
  }

  // epilogue: C/D layout col=lane&15 (n), row=quad*4+reg (j).
  // reduce over j within block, one atomicAdd per (n, block). 8 adders/address.
#pragma unroll
  for (int ni = 0; ni < 4; ni++) {
    float v = 0.0f;
#pragma unroll
    for (int mi = 0; mi < 4; mi++) {
      const int jb = aRow0 + waveM * 64 + mi * 16 + quad * 4;
      union { float4_t v4; float f[4]; } u;
      u.v4 = acc[mi][ni];
#pragma unroll
      for (int r = 0; r < 4; r++)
        v += Wmta[jb + r] * tanh_fast(u.f[r]);
    }
    v += __shfl_xor(v, 16);
    v += __shfl_xor(v, 32);
    if (quad == 0) {
      const int n = bRow0 + waveN * 64 + ni * 16 + col;
      atomicAdd(&s[n], v);
    }
  }
}

// ---- softmax stats, stage 1: 32 blocks x 256 threads, online (m,p) partials
__global__ __launch_bounds__(256) void k_stats1(const float* __restrict__ s,
                                                float* __restrict__ pstat) {
  const int tid = threadIdx.x;
  const int lane = tid & 63;
  const int wvi = tid >> 6;
  __shared__ float smM[4], smP[4];
  const float4* s4 = (const float4*)s;

  float4 v = s4[blockIdx.x * 256 + tid];
  float m = fmaxf(fmaxf(v.x, v.y), fmaxf(v.z, v.w));
  float p = __expf(v.x - m) + __expf(v.y - m) + __expf(v.z - m) + __expf(v.w - m);
  for (int o = 32; o > 0; o >>= 1) {
    float om = __shfl_xor(m, o);
    float op = __shfl_xor(p, o);
    float nm = fmaxf(m, om);
    p = p * __expf(m - nm) + op * __expf(om - nm);
    m = nm;
  }
  if (lane == 0) { smM[wvi] = m; smP[wvi] = p; }
  __syncthreads();
  if (tid == 0) {
    float gm = fmaxf(fmaxf(smM[0], smM[1]), fmaxf(smM[2], smM[3]));
    float sum = 0.f;
    for (int w = 0; w < 4; w++) sum += smP[w] * __expf(smM[w] - gm);
    pstat[blockIdx.x * 2]     = gm;
    pstat[blockIdx.x * 2 + 1] = sum;
  }
}

// ---- softmax stats, stage 2: merge 32 partials ----
__global__ __launch_bounds__(64) void k_stats2(const float* __restrict__ pstat,
                                               float* __restrict__ stats) {
  const int tid = threadIdx.x;  // one wave
  float m = -3.4e38f, p = 0.0f;
  if (tid < 32) { m = pstat[tid * 2]; p = pstat[tid * 2 + 1]; }
  for (int o = 32; o > 0; o >>= 1) {
    float om = __shfl_xor(m, o);
    float op = __shfl_xor(p, o);
    float nm = fmaxf(m, om);
    p = p * __expf(m - nm) + op * __expf(om - nm);
    m = nm;
  }
  if (tid == 0) { stats[0] = m; stats[1] = 1.0f / p; }
}

// ---- pooling: t[d] += sum_{n in blk} w[n]*V[n,d], atomics, hot blocks only.
// Weights staged through LDS first (kills 128 serial dependent global loads);
// softmax is near-one-hot so almost all blocks exit without touching V or t.
// Skipped w<1e-12 rows contribute < 1.6e-7 total.
__global__ __launch_bounds__(256) void k_pool(const float* __restrict__ V,
                                              const float* __restrict__ s,
                                              const float* __restrict__ stats,
                                              float* __restrict__ t) {
  __shared__ float wsm[128];
  __shared__ int hot;
  const int tid = threadIdx.x;
  if (tid == 0) hot = 0;
  __syncthreads();
  const float mx = stats[0], inv = stats[1];
  const int n0 = blockIdx.x * 128;
  if (tid < 128) {
    const float w = __expf(s[n0 + tid] - mx) * inv;
    wsm[tid] = w;
    if (w > 1e-12f) atomicOr(&hot, 1);
  }
  __syncthreads();
  if (hot == 0) return;

  float acc[8] = {0.f, 0.f, 0.f, 0.f, 0.f, 0.f, 0.f, 0.f};
  for (int r = 0; r < 128; ++r) {
    const float w = wsm[r];     // block-uniform branch
    if (w > 1e-12f) {
      const float4* vp = (const float4*)&V[(size_t)(n0 + r) * DIM + tid * 8];
      float4 va = vp[0], vb = vp[1];
      acc[0] += w * va.x; acc[1] += w * va.y; acc[2] += w * va.z; acc[3] += w * va.w;
      acc[4] += w * vb.x; acc[5] += w * vb.y; acc[6] += w * vb.z; acc[7] += w * vb.w;
    }
  }
#pragma unroll
  for (int j = 0; j < 8; ++j) atomicAdd(&t[tid * 8 + j], acc[j]);
}

// ---- final linear: out[c] = W[c,:] . t  (one block; t is only 8 KB)
__global__ __launch_bounds__(256) void k_final(const float* __restrict__ t,
                                               const float* __restrict__ W,
                                               float* __restrict__ out) {
  const int tid = threadIdx.x;
  const float4* t4 = (const float4*)t;
  const float4 ta = t4[tid * 2], tb = t4[tid * 2 + 1];
  float pc[NCLS];
#pragma unroll
  for (int c = 0; c < NCLS; ++c) {
    const float4* w4 = (const float4*)&W[(size_t)c * DIM + tid * 8];
    const float4 wa = w4[0], wb = w4[1];
    pc[c] = wa.x * ta.x + wa.y * ta.y + wa.z * ta.z + wa.w * ta.w +
            wb.x * tb.x + wb.y * tb.y + wb.z * tb.z + wb.w * tb.w;
  }
  __shared__ float sred[4][NCLS];
  const int lane = tid & 63, wvi = tid >> 6;
#pragma unroll
  for (int c = 0; c < NCLS; ++c)
    for (int o = 32; o > 0; o >>= 1) pc[c] += __shfl_xor(pc[c], o);
  if (lane == 0)
#pragma unroll
    for (int c = 0; c < NCLS; ++c) sred[wvi][c] = pc[c];
  __syncthreads();
  if (tid < NCLS)
    out[tid] = sred[0][tid] + sred[1][tid] + sred[2][tid] + sred[3][tid];
}

extern "C" void kernel_launch(void* const* d_in, const int* in_sizes, int n_in,
                              void* d_out, int out_size, void* d_ws, size_t ws_size,
                              hipStream_t stream) {
  const float* Vp   = (const float*)d_in[0];  // [N, 2048]
  const float* Ut   = (const float*)d_in[1];  // [512, 2048]
  const float* Wmta = (const float*)d_in[2];  // [1, 512]
  const float* W    = (const float*)d_in[3];  // [4, 2048]
  float* out = (float*)d_out;

  char* ws = (char*)d_ws;
  _Float16* Uhi  = (_Float16*)(ws + OFF_UHI);
  float*    sBuf = (float*)(ws + OFF_S);
  float*    stat = (float*)(ws + OFF_STAT);
  float*    pstat= (float*)(ws + OFF_PSTAT);
  float*    tvec = (float*)(ws + OFF_T);

  hipMemsetAsync(sBuf, 0, (size_t)N_INST * 4, stream);
  hipMemsetAsync(tvec, 0, (size_t)DIM * 4, stream);

  k_cvt<<<(DP * DIM / 8) / 256, 256, 0, stream>>>((const float4*)Ut, (half8_t*)Uhi);
  k_score_gemm<<<(DP / 128) * (N_INST / 128), 256, 0, stream>>>(Uhi, Vp, Wmta, sBuf);
  k_stats1<<<32, 256, 0, stream>>>(sBuf, pstat);
  k_stats2<<<1, 64, 0, stream>>>(pstat, stat);
  k_pool<<<N_INST / 128, 256, 0, stream>>>(Vp, sBuf, stat, tvec);
  k_final<<<1, 256, 0, stream>>>(tvec, W, out);
}

// Round 3
// 507.773 us; speedup vs baseline: 1.0583x; 1.0583x over previous
//
#include <hip/hip_runtime.h>

// Problem constants (fixed shapes from reference setup_inputs)
#define N_INST 32768
#define DIM    2048
#define DP     512
#define NCLS   4

typedef _Float16 half8_t  __attribute__((ext_vector_type(8)));
typedef float    float4_t __attribute__((ext_vector_type(4)));

// Workspace layout (bytes). Total ~2.3 MB.
#define OFF_UHI   0ull                              // DP*DIM fp16 = 2 MB
#define OFF_S     (OFF_UHI  + (size_t)DP*DIM*2)     // N fp32 = 128 KB
#define OFF_STAT  (OFF_S    + (size_t)N_INST*4)     // 2 fp32
#define OFF_PSTAT (OFF_STAT + 256ull)               // 32*2 fp32 partial stats
#define OFF_T     (OFF_PSTAT+ 256ull)               // DIM fp32 pooled vector

__device__ __forceinline__ float tanh_fast(float x) {
  // tanh(x) = 1 - 2/(exp(2x)+1); exp overflow->inf gives exact +/-1 limits
  float e = __expf(2.0f * x);
  return 1.0f - 2.0f / (e + 1.0f);
}

// async global->LDS, 16B per lane. LDS dest is wave-uniform base + lane*16.
typedef const unsigned int __attribute__((address_space(1)))* gas_t;
typedef unsigned int       __attribute__((address_space(3)))* las_t;
__device__ __forceinline__ void gl16(const void* g, void* l) {
  __builtin_amdgcn_global_load_lds((gas_t)g, (las_t)l, 16, 0, 0);
}

// ---- fp32 -> fp16 convert (U only; 8 elems/thread) ----
__global__ __launch_bounds__(256) void k_cvt(const float4* __restrict__ in,
                                             half8_t* __restrict__ out) {
  int i = blockIdx.x * 256 + threadIdx.x;
  float4 a = in[2 * i], b = in[2 * i + 1];
  half8_t h;
  h[0] = (_Float16)a.x; h[1] = (_Float16)a.y;
  h[2] = (_Float16)a.z; h[3] = (_Float16)a.w;
  h[4] = (_Float16)b.x; h[5] = (_Float16)b.y;
  h[6] = (_Float16)b.z; h[7] = (_Float16)b.w;
  out[i] = h;
}

// ---- fused score GEMM, 2-phase double-buffered (T3 minimum recipe):
// s[n] = sum_j Wmta[j]*tanh( Uhi[j,:] . V[n,:] )
// 128x128 tile, BK=32, 4 waves (2x2), wave tile 64x64 = 4x4 MFMA 16x16x32 f16.
// Both operands staged global->LDS via global_load_lds_dwordx4. Double-buffered:
// next tile's loads issue BEFORE the current tile's compute, so the compiler's
// vmcnt(0)-before-barrier drain overlaps a full compute phase (12 ds_read_b128
// + 16 cvt + 16 MFMA per wave) instead of stalling serially. One barrier per
// K-step. B (V) stays fp32 in LDS; fp16 cvt at fragment-read (v_cvt_pkrtz).
//
// Frag-read bank balance: XOR swizzle of the 16B slot index within each LDS
// row, folded into the per-lane GLOBAL source address (LDS dest of
// global_load_lds must stay linear). Readers apply the same XOR.
// A (64B rows, 4 slots): slot ^= (row>>1)&3. B (128B rows, 8 slots):
// slot ^= row&7. Both patterns are balanced at 8 dword-accesses/bank (the
// wave64 b128 minimum).
__global__ __launch_bounds__(256) void k_score_gemm(
    const _Float16* __restrict__ Uhi, const float* __restrict__ V,
    const float* __restrict__ Wmta, float* __restrict__ s) {
  __shared__ _Float16 lA[2][128 * 32];   // 2 x 8 KB  (fp16, row stride 64 B)
  __shared__ float    lB[2][128 * 32];   // 2 x 16 KB (fp32, row stride 128 B)

  const int tid  = threadIdx.x;
  const int lane = tid & 63;
  const int wv   = tid >> 6;        // 0..3
  const int waveM = wv >> 1;        // 0..1
  const int waveN = wv & 1;         // 0..1
  const int quad = lane >> 4;       // 0..3
  const int col  = lane & 15;

  // XCD-aware swizzle: 4 mb-siblings of one nb sit 8 apart in blockIdx
  // (same XCD under %8 round-robin), so a V tile is fetched ~once per XCD.
  const int b   = blockIdx.x;
  const int grp = b >> 5;
  const int win = b & 31;
  const int mb  = win >> 3;             // 0..3
  const int nb  = grp * 8 + (win & 7);  // 0..255

  const int aRow0  = mb * 128;
  const int bRow0  = nb * 128;
  const int kStart = (nb & 63) << 5;    // K-phase stagger (decorrelates L2/HBM)

  // ---- staging source addresses (swizzle pre-applied) ----
  // A: 8 chunks x 1024B; chunk ch = wv*2+{0,1}; lane l -> row ch*16 + (l>>2),
  //    physical slot l&3 sources logical slot (l&3)^((row>>1)&3).
  const int rA0 = wv * 32 + (lane >> 2);           // rows wv*32 .. +15
  const int sA  = (lane & 3) ^ ((rA0 >> 1) & 3);   // same for row+16
  const _Float16* gA0 = Uhi + (size_t)(aRow0 + rA0) * DIM + sA * 8;
  const _Float16* gA1 = gA0 + (size_t)16 * DIM;
  const int dA0 = (wv * 2 + 0) * 512;   // element offsets within one lA buffer
  const int dA1 = (wv * 2 + 1) * 512;

  // B: 16 chunks x 1024B; chunk ch = wv*4+j; lane l -> row ch*8 + (l>>3),
  //    physical slot l&7 sources logical slot (l&7)^(row&7).
  const int rB0 = wv * 32 + (lane >> 3);      // rows wv*32 .. +7
  const int sB  = (lane & 7) ^ (rB0 & 7);     // row&7 invariant under +8
  const float* gB0 = V + (size_t)(bRow0 + rB0) * DIM + sB * 4;
  const float* gB1 = gB0 + (size_t)8  * DIM;
  const float* gB2 = gB0 + (size_t)16 * DIM;
  const float* gB3 = gB0 + (size_t)24 * DIM;
  const int dB0 = (wv * 4 + 0) * 256;
  const int dB1 = (wv * 4 + 1) * 256;
  const int dB2 = (wv * 4 + 2) * 256;
  const int dB3 = (wv * 4 + 3) * 256;

  // ---- fragment-read byte offsets (precomputed, constant across K-loop) ----
  int offA[4];
#pragma unroll
  for (int mi = 0; mi < 4; ++mi) {
    const int r = waveM * 64 + mi * 16 + col;
    offA[mi] = r * 64 + ((quad ^ ((r >> 1) & 3)) << 4);
  }
  int offB[4];   // second 16B of the pair is offB ^ 16 (slot^1)
#pragma unroll
  for (int ni = 0; ni < 4; ++ni) {
    const int r = waveN * 64 + ni * 16 + col;
    offB[ni] = r * 128 + ((((quad << 1)) ^ (r & 7)) << 4);
  }

  float4_t acc[4][4];
  const float4_t z4 = {0.f, 0.f, 0.f, 0.f};
#pragma unroll
  for (int i = 0; i < 4; i++)
#pragma unroll
    for (int j = 0; j < 4; j++) acc[i][j] = z4;

#define STAGE(buf, k) do {                       \
    gl16(gA0 + (k), &lA[buf][dA0]);              \
    gl16(gA1 + (k), &lA[buf][dA1]);              \
    gl16(gB0 + (k), &lB[buf][dB0]);              \
    gl16(gB1 + (k), &lB[buf][dB1]);              \
    gl16(gB2 + (k), &lB[buf][dB2]);              \
    gl16(gB3 + (k), &lB[buf][dB3]);              \
  } while (0)

#define COMPUTE(buf) do {                                                  \
    const char* lAc = (const char*)&lA[buf][0];                            \
    const char* lBc = (const char*)&lB[buf][0];                            \
    half8_t af[4];                                                         \
    _Pragma("unroll")                                                      \
    for (int mi = 0; mi < 4; ++mi)                                         \
      af[mi] = *(const half8_t*)(lAc + offA[mi]);                          \
    _Pragma("unroll")                                                      \
    for (int ni = 0; ni < 4; ++ni) {                                       \
      const float4_t x = *(const float4_t*)(lBc + offB[ni]);               \
      const float4_t y = *(const float4_t*)(lBc + (offB[ni] ^ 16));        \
      const auto c0 = __builtin_amdgcn_cvt_pkrtz(x[0], x[1]);              \
      const auto c1 = __builtin_amdgcn_cvt_pkrtz(x[2], x[3]);              \
      const auto c2 = __builtin_amdgcn_cvt_pkrtz(y[0], y[1]);              \
      const auto c3 = __builtin_amdgcn_cvt_pkrtz(y[2], y[3]);              \
      half8_t bf;                                                          \
      bf[0] = (_Float16)c0[0]; bf[1] = (_Float16)c0[1];                    \
      bf[2] = (_Float16)c1[0]; bf[3] = (_Float16)c1[1];                    \
      bf[4] = (_Float16)c2[0]; bf[5] = (_Float16)c2[1];                    \
      bf[6] = (_Float16)c3[0]; bf[7] = (_Float16)c3[1];                    \
      _Pragma("unroll")                                                    \
      for (int mi = 0; mi < 4; ++mi)                                       \
        acc[mi][ni] = __builtin_amdgcn_mfma_f32_16x16x32_f16(              \
            af[mi], bf, acc[mi][ni], 0, 0, 0);                             \
    }                                                                      \
  } while (0)

  // prologue: stage tile 0 into buf0
  STAGE(0, kStart);

  for (int kk = 0; kk < 32; ++kk) {
    const int kB = (kStart + (2 * kk + 1) * 32) & (DIM - 1);
    const int kC = (kStart + (2 * kk + 2) * 32) & (DIM - 1);
    __syncthreads();          // buf0 resident (vmcnt drained); buf1 reads done
    STAGE(1, kB);             // prefetch next tile — latency hides under COMPUTE
    COMPUTE(0);
    __syncthreads();          // buf1 resident; all reads of buf0 done
    if (kk < 31) STAGE(0, kC);
    COMPUTE(1);
  }
#undef STAGE
#undef COMPUTE

  // epilogue: C/D layout col=lane&15 (n), row=quad*4+reg (j).
  // reduce over j within block, one atomicAdd per (n, block). 8 adders/address.
#pragma unroll
  for (int ni = 0; ni < 4; ni++) {
    float v = 0.0f;
#pragma unroll
    for (int mi = 0; mi < 4; mi++) {
      const int jb = aRow0 + waveM * 64 + mi * 16 + quad * 4;
      union { float4_t v4; float f[4]; } u;
      u.v4 = acc[mi][ni];
#pragma unroll
      for (int r = 0; r < 4; r++)
        v += Wmta[jb + r] * tanh_fast(u.f[r]);
    }
    v += __shfl_xor(v, 16);
    v += __shfl_xor(v, 32);
    if (quad == 0) {
      const int n = bRow0 + waveN * 64 + ni * 16 + col;
      atomicAdd(&s[n], v);
    }
  }
}

// ---- softmax stats, stage 1: 32 blocks x 256 threads, online (m,p) partials
__global__ __launch_bounds__(256) void k_stats1(const float* __restrict__ s,
                                                float* __restrict__ pstat) {
  const int tid = threadIdx.x;
  const int lane = tid & 63;
  const int wvi = tid >> 6;
  __shared__ float smM[4], smP[4];
  const float4* s4 = (const float4*)s;

  float4 v = s4[blockIdx.x * 256 + tid];
  float m = fmaxf(fmaxf(v.x, v.y), fmaxf(v.z, v.w));
  float p = __expf(v.x - m) + __expf(v.y - m) + __expf(v.z - m) + __expf(v.w - m);
  for (int o = 32; o > 0; o >>= 1) {
    float om = __shfl_xor(m, o);
    float op = __shfl_xor(p, o);
    float nm = fmaxf(m, om);
    p = p * __expf(m - nm) + op * __expf(om - nm);
    m = nm;
  }
  if (lane == 0) { smM[wvi] = m; smP[wvi] = p; }
  __syncthreads();
  if (tid == 0) {
    float gm = fmaxf(fmaxf(smM[0], smM[1]), fmaxf(smM[2], smM[3]));
    float sum = 0.f;
    for (int w = 0; w < 4; w++) sum += smP[w] * __expf(smM[w] - gm);
    pstat[blockIdx.x * 2]     = gm;
    pstat[blockIdx.x * 2 + 1] = sum;
  }
}

// ---- softmax stats, stage 2: merge 32 partials ----
__global__ __launch_bounds__(64) void k_stats2(const float* __restrict__ pstat,
                                               float* __restrict__ stats) {
  const int tid = threadIdx.x;  // one wave
  float m = -3.4e38f, p = 0.0f;
  if (tid < 32) { m = pstat[tid * 2]; p = pstat[tid * 2 + 1]; }
  for (int o = 32; o > 0; o >>= 1) {
    float om = __shfl_xor(m, o);
    float op = __shfl_xor(p, o);
    float nm = fmaxf(m, om);
    p = p * __expf(m - nm) + op * __expf(om - nm);
    m = nm;
  }
  if (tid == 0) { stats[0] = m; stats[1] = 1.0f / p; }
}

// ---- pooling: t[d] += sum_{n in blk} w[n]*V[n,d], atomics, hot blocks only.
// Weights staged through LDS first (kills 128 serial dependent global loads);
// softmax is near-one-hot so almost all blocks exit without touching V or t.
// Skipped w<1e-12 rows contribute < 1.6e-7 total.
__global__ __launch_bounds__(256) void k_pool(const float* __restrict__ V,
                                              const float* __restrict__ s,
                                              const float* __restrict__ stats,
                                              float* __restrict__ t) {
  __shared__ float wsm[128];
  __shared__ int hot;
  const int tid = threadIdx.x;
  if (tid == 0) hot = 0;
  __syncthreads();
  const float mx = stats[0], inv = stats[1];
  const int n0 = blockIdx.x * 128;
  if (tid < 128) {
    const float w = __expf(s[n0 + tid] - mx) * inv;
    wsm[tid] = w;
    if (w > 1e-12f) atomicOr(&hot, 1);
  }
  __syncthreads();
  if (hot == 0) return;

  float acc[8] = {0.f, 0.f, 0.f, 0.f, 0.f, 0.f, 0.f, 0.f};
  for (int r = 0; r < 128; ++r) {
    const float w = wsm[r];     // block-uniform branch
    if (w > 1e-12f) {
      const float4* vp = (const float4*)&V[(size_t)(n0 + r) * DIM + tid * 8];
      float4 va = vp[0], vb = vp[1];
      acc[0] += w * va.x; acc[1] += w * va.y; acc[2] += w * va.z; acc[3] += w * va.w;
      acc[4] += w * vb.x; acc[5] += w * vb.y; acc[6] += w * vb.z; acc[7] += w * vb.w;
    }
  }
#pragma unroll
  for (int j = 0; j < 8; ++j) atomicAdd(&t[tid * 8 + j], acc[j]);
}

// ---- final linear: out[c] = W[c,:] . t  (one block; t is only 8 KB)
__global__ __launch_bounds__(256) void k_final(const float* __restrict__ t,
                                               const float* __restrict__ W,
                                               float* __restrict__ out) {
  const int tid = threadIdx.x;
  const float4* t4 = (const float4*)t;
  const float4 ta = t4[tid * 2], tb = t4[tid * 2 + 1];
  float pc[NCLS];
#pragma unroll
  for (int c = 0; c < NCLS; ++c) {
    const float4* w4 = (const float4*)&W[(size_t)c * DIM + tid * 8];
    const float4 wa = w4[0], wb = w4[1];
    pc[c] = wa.x * ta.x + wa.y * ta.y + wa.z * ta.z + wa.w * ta.w +
            wb.x * tb.x + wb.y * tb.y + wb.z * tb.z + wb.w * tb.w;
  }
  __shared__ float sred[4][NCLS];
  const int lane = tid & 63, wvi = tid >> 6;
#pragma unroll
  for (int c = 0; c < NCLS; ++c)
    for (int o = 32; o > 0; o >>= 1) pc[c] += __shfl_xor(pc[c], o);
  if (lane == 0)
#pragma unroll
    for (int c = 0; c < NCLS; ++c) sred[wvi][c] = pc[c];
  __syncthreads();
  if (tid < NCLS)
    out[tid] = sred[0][tid] + sred[1][tid] + sred[2][tid] + sred[3][tid];
}

extern "C" void kernel_launch(void* const* d_in, const int* in_sizes, int n_in,
                              void* d_out, int out_size, void* d_ws, size_t ws_size,
                              hipStream_t stream) {
  const float* Vp   = (const float*)d_in[0];  // [N, 2048]
  const float* Ut   = (const float*)d_in[1];  // [512, 2048]
  const float* Wmta = (const float*)d_in[2];  // [1, 512]
  const float* W    = (const float*)d_in[3];  // [4, 2048]
  float* out = (float*)d_out;

  char* ws = (char*)d_ws;
  _Float16* Uhi  = (_Float16*)(ws + OFF_UHI);
  float*    sBuf = (float*)(ws + OFF_S);
  float*    stat = (float*)(ws + OFF_STAT);
  float*    pstat= (float*)(ws + OFF_PSTAT);
  float*    tvec = (float*)(ws + OFF_T);

  hipMemsetAsync(sBuf, 0, (size_t)N_INST * 4, stream);
  hipMemsetAsync(tvec, 0, (size_t)DIM * 4, stream);

  k_cvt<<<(DP * DIM / 8) / 256, 256, 0, stream>>>((const float4*)Ut, (half8_t*)Uhi);
  k_score_gemm<<<(DP / 128) * (N_INST / 128), 256, 0, stream>>>(Uhi, Vp, Wmta, sBuf);
  k_stats1<<<32, 256, 0, stream>>>(sBuf, pstat);
  k_stats2<<<1, 64, 0, stream>>>(pstat, stat);
  k_pool<<<N_INST / 128, 256, 0, stream>>>(Vp, sBuf, stat, tvec);
  k_final<<<1, 256, 0, stream>>>(tvec, W, out);
}

// Round 4
// 439.679 us; speedup vs baseline: 1.2222x; 1.1549x over previous
//
#include <hip/hip_runtime.h>

// Problem constants (fixed shapes from reference setup_inputs)
#define N_INST 32768
#define DIM    2048
#define DP     512
#define NCLS   4

typedef _Float16 half8_t  __attribute__((ext_vector_type(8)));
typedef float    float4_t __attribute__((ext_vector_type(4)));

// Workspace layout (bytes). Total ~2.2 MB.
#define OFF_UHI   0ull                              // DP*DIM fp16 = 2 MB
#define OFF_S     (OFF_UHI  + (size_t)DP*DIM*2)     // N fp32 = 128 KB
#define OFF_STAT  (OFF_S    + (size_t)N_INST*4)     // 2 fp32

__device__ __forceinline__ float tanh_fast(float x) {
  // tanh(x) = 1 - 2/(exp(2x)+1); exp overflow->inf gives exact +/-1 limits
  float e = __expf(2.0f * x);
  return 1.0f - 2.0f / (e + 1.0f);
}

// async global->LDS, 16B per lane. LDS dest is wave-uniform base; HW adds lane*16.
typedef const unsigned int __attribute__((address_space(1)))* gas_t;
typedef unsigned int       __attribute__((address_space(3)))* las_t;
__device__ __forceinline__ void gl16(const void* g, void* l) {
  __builtin_amdgcn_global_load_lds((gas_t)g, (las_t)l, 16, 0, 0);
}

// ---- fp32 -> fp16 convert of U (8 elems/thread) + zero sBuf (fused memset) ----
__global__ __launch_bounds__(256) void k_cvt(const float4* __restrict__ in,
                                             half8_t* __restrict__ out,
                                             float4* __restrict__ s4z) {
  int i = blockIdx.x * 256 + threadIdx.x;     // 0..131071
  float4 a = in[2 * i], b = in[2 * i + 1];
  half8_t h;
  h[0] = (_Float16)a.x; h[1] = (_Float16)a.y;
  h[2] = (_Float16)a.z; h[3] = (_Float16)a.w;
  h[4] = (_Float16)b.x; h[5] = (_Float16)b.y;
  h[6] = (_Float16)b.z; h[7] = (_Float16)b.w;
  out[i] = h;
  if (i < N_INST / 4) s4z[i] = make_float4(0.f, 0.f, 0.f, 0.f);
}

// ---- fused score GEMM, 256x256 tile, BK=64, 8 waves (2Mx4N), wave tile 128x64.
// s[n] = sum_j Wmta[j]*tanh( Uhi[j,:] . V[n,:] )
// Rationale: 64x64 wave tiles are LDS-BW-bound (8KB frag reads per 80 MFMA
// cycles); 128x64 halves fragment bytes per FLOP. Grid = 256 = 1 block/CU
// (no tail). LDS 128 KB: 2(dbuf) x [A 256x64 fp16 (32KB) + B 256x64 fp16
// (32KB)]. A staged via global_load_lds_dwordx4; B (V fp32) reg-staged with
// cvt_pkrtz -> fp16 ds_write, T14 async-split: tile t+2's global loads issue
// BEFORE COMPUTE(t) so HBM latency hides under a full compute phase.
//
// Swizzle (both-sides, rule 21): rows are 128 B = 8 16B-slots; physical slot
// p holds logical slot p^(row&7). For A this is pre-applied to the GLOBAL
// source address (gl_lds dest stays linear); for B it's applied to the
// ds_write address. Fragment readers apply the same XOR -> balanced banks.
__global__ __launch_bounds__(512, 2) void k_score_gemm(
    const _Float16* __restrict__ Uhi, const float* __restrict__ V,
    const float* __restrict__ Wmta, float* __restrict__ s) {
  __shared__ _Float16 lA[2][256 * 64];   // 2 x 32 KB
  __shared__ _Float16 lB[2][256 * 64];   // 2 x 32 KB

  const int tid  = threadIdx.x;
  const int lane = tid & 63;
  const int wv   = tid >> 6;        // 0..7
  const int waveM = wv >> 2;        // 0..1
  const int waveN = wv & 3;         // 0..3
  const int quad = lane >> 4;       // 0..3
  const int col  = lane & 15;

  // XCD swizzle: the 2 mb-siblings of one nb sit 8 apart in blockIdx (same
  // XCD under %8 round-robin) so a V n-strip is fetched ~once per XCD.
  const int b   = blockIdx.x;
  const int grp = b >> 4;
  const int win = b & 15;
  const int mb  = win >> 3;             // 0..1
  const int nb  = grp * 8 + (win & 7);  // 0..127

  const int aRow0  = mb * 256;
  const int bRow0  = nb * 256;
  const int kStart = (nb & 31) << 6;    // K-phase stagger

  // ---- A staging: 32 chunks of 1KB (8 rows x 128B); 4 chunks/wave ----
  const int rsub = lane >> 3;               // 0..7 row within chunk
  const int sswz = (lane & 7) ^ rsub;       // pre-swizzled source slot
  const _Float16* gA[4];
  int dA[4];                                 // element offset of chunk base
#pragma unroll
  for (int i2 = 0; i2 < 4; ++i2) {
    const int c = wv * 4 + i2;               // chunk 0..31
    gA[i2] = Uhi + (size_t)(aRow0 + c * 8 + rsub) * DIM + sswz * 8;
    dA[i2] = c * 512;
  }

  // ---- B staging: thread owns half a row (32 floats -> 32 fp16) ----
  const int rw = tid >> 1;                  // 0..255 (row = n within tile)
  const int hw = tid & 1;                   // which 32-float half
  const float* gB = V + (size_t)(bRow0 + rw) * DIM + hw * 32;
  int wOffB[4];                             // byte offsets (swizzled) in a bufB
#pragma unroll
  for (int p = 0; p < 4; ++p)
    wOffB[p] = rw * 128 + ((((hw << 2) | p) ^ (rw & 7)) << 4);

  // ---- fragment-read byte offsets (kh toggles byte^64 == logical slot^4) ----
  const int fsw = (quad ^ (col & 7)) << 4;
  int offA[8], offB[4];
#pragma unroll
  for (int mi = 0; mi < 8; ++mi)
    offA[mi] = (waveM * 128 + mi * 16 + col) * 128 + fsw;
#pragma unroll
  for (int ni = 0; ni < 4; ++ni)
    offB[ni] = (waveN * 64 + ni * 16 + col) * 128 + fsw;

  float4_t acc[8][4];
  const float4_t z4 = {0.f, 0.f, 0.f, 0.f};
#pragma unroll
  for (int i = 0; i < 8; i++)
#pragma unroll
    for (int j = 0; j < 4; j++) acc[i][j] = z4;

  float4 rb[8];   // in-flight B tile (32 floats)

#define KOF(t) ((kStart + (t) * 64) & (DIM - 1))

#define LOADB(kk) do {                                                     \
    const float4* p4 = (const float4*)(gB + (kk));                         \
    _Pragma("unroll")                                                      \
    for (int j = 0; j < 8; ++j) rb[j] = p4[j];                             \
  } while (0)

#define WRITEB(CUR) do {                                                   \
    char* base = (char*)&lB[CUR][0];                                       \
    _Pragma("unroll")                                                      \
    for (int p = 0; p < 4; ++p) {                                          \
      const auto c0 = __builtin_amdgcn_cvt_pkrtz(rb[2*p].x,   rb[2*p].y);  \
      const auto c1 = __builtin_amdgcn_cvt_pkrtz(rb[2*p].z,   rb[2*p].w);  \
      const auto c2 = __builtin_amdgcn_cvt_pkrtz(rb[2*p+1].x, rb[2*p+1].y);\
      const auto c3 = __builtin_amdgcn_cvt_pkrtz(rb[2*p+1].z, rb[2*p+1].w);\
      half8_t h;                                                           \
      h[0] = (_Float16)c0[0]; h[1] = (_Float16)c0[1];                      \
      h[2] = (_Float16)c1[0]; h[3] = (_Float16)c1[1];                      \
      h[4] = (_Float16)c2[0]; h[5] = (_Float16)c2[1];                      \
      h[6] = (_Float16)c3[0]; h[7] = (_Float16)c3[1];                      \
      *(half8_t*)(base + wOffB[p]) = h;                                    \
    }                                                                      \
  } while (0)

#define STAGEA(CUR, kk) do {                                               \
    gl16(gA[0] + (kk), &lA[CUR][dA[0]]);                                   \
    gl16(gA[1] + (kk), &lA[CUR][dA[1]]);                                   \
    gl16(gA[2] + (kk), &lA[CUR][dA[2]]);                                   \
    gl16(gA[3] + (kk), &lA[CUR][dA[3]]);                                   \
  } while (0)

#define COMPUTE(CUR) do {                                                  \
    const char* pA = (const char*)&lA[CUR][0];                             \
    const char* pB = (const char*)&lB[CUR][0];                             \
    _Pragma("unroll")                                                      \
    for (int kh = 0; kh < 2; ++kh) {                                       \
      half8_t af[8], bf[4];                                                \
      _Pragma("unroll")                                                    \
      for (int mi = 0; mi < 8; ++mi)                                       \
        af[mi] = *(const half8_t*)(pA + (offA[mi] ^ (kh << 6)));           \
      _Pragma("unroll")                                                    \
      for (int ni = 0; ni < 4; ++ni)                                       \
        bf[ni] = *(const half8_t*)(pB + (offB[ni] ^ (kh << 6)));           \
      _Pragma("unroll")                                                    \
      for (int mi = 0; mi < 8; ++mi)                                       \
        _Pragma("unroll")                                                  \
        for (int ni = 0; ni < 4; ++ni)                                     \
          acc[mi][ni] = __builtin_amdgcn_mfma_f32_16x16x32_f16(            \
              af[mi], bf[ni], acc[mi][ni], 0, 0, 0);                       \
    }                                                                      \
  } while (0)

  // ---- prologue: tile0 resident in buf0; rb holds tile1 ----
  LOADB(KOF(0));
  STAGEA(0, KOF(0));
  WRITEB(0);                    // compiler waits rb's vmcnt before cvt
  LOADB(KOF(1));
  __syncthreads();              // drains gl16 + ds_writes (and rb loads)

  // ---- main loop: 32 K-tiles, 2 per trip, 1 barrier per tile ----
  for (int t = 0; t < 32; t += 2) {
    // iter t (compute buf0)
    if (t < 31)  { STAGEA(1, KOF(t + 1)); WRITEB(1); }   // rb = tile t+1
    if (t < 30)  LOADB(KOF(t + 2));                      // issue early (T14)
    COMPUTE(0);
    __syncthreads();
    // iter t+1 (compute buf1)
    if (t + 1 < 31) { STAGEA(0, KOF(t + 2)); WRITEB(0); }
    if (t + 1 < 30) LOADB(KOF(t + 3));
    COMPUTE(1);
    __syncthreads();
  }
#undef KOF
#undef LOADB
#undef WRITEB
#undef STAGEA
#undef COMPUTE

  // epilogue: C/D layout col=lane&15 (n), row=quad*4+reg (j).
  // reduce over j within block, one atomicAdd per (n, waveM). 4 adders/address.
#pragma unroll
  for (int ni = 0; ni < 4; ni++) {
    float v = 0.0f;
#pragma unroll
    for (int mi = 0; mi < 8; mi++) {
      const int jb = aRow0 + waveM * 128 + mi * 16 + quad * 4;
      union { float4_t v4; float f[4]; } u;
      u.v4 = acc[mi][ni];
#pragma unroll
      for (int r = 0; r < 4; r++)
        v += Wmta[jb + r] * tanh_fast(u.f[r]);
    }
    v += __shfl_xor(v, 16);
    v += __shfl_xor(v, 32);
    if (quad == 0) {
      const int n = bRow0 + waveN * 64 + ni * 16 + col;
      atomicAdd(&s[n], v);
    }
  }
}

// ---- softmax stats, single block (fused stage1+stage2) + zero out[] ----
__global__ __launch_bounds__(1024) void k_stats(const float* __restrict__ s,
                                                float* __restrict__ stats,
                                                float* __restrict__ out) {
  const int tid = threadIdx.x;
  const int lane = tid & 63;
  const int wvi = tid >> 6;            // 0..15
  __shared__ float smM[16], smP[16];
  const float4* s4 = (const float4*)s;

  if (tid < NCLS) out[tid] = 0.f;      // pool accumulates into out atomically

  float m = -3.4e38f, p = 0.0f;
#pragma unroll
  for (int j = 0; j < 8; ++j) {
    float4 v = s4[tid * 8 + j];
    float lm = fmaxf(fmaxf(v.x, v.y), fmaxf(v.z, v.w));
    float lp = __expf(v.x - lm) + __expf(v.y - lm) +
               __expf(v.z - lm) + __expf(v.w - lm);
    float nm = fmaxf(m, lm);
    p = p * __expf(m - nm) + lp * __expf(lm - nm);
    m = nm;
  }
  for (int o = 32; o > 0; o >>= 1) {
    float om = __shfl_xor(m, o);
    float op = __shfl_xor(p, o);
    float nm = fmaxf(m, om);
    p = p * __expf(m - nm) + op * __expf(om - nm);
    m = nm;
  }
  if (lane == 0) { smM[wvi] = m; smP[wvi] = p; }
  __syncthreads();
  if (tid == 0) {
    float gm = smM[0];
    for (int w = 1; w < 16; w++) gm = fmaxf(gm, smM[w]);
    float sum = 0.f;
    for (int w = 0; w < 16; w++) sum += smP[w] * __expf(smM[w] - gm);
    stats[0] = gm;
    stats[1] = 1.0f / sum;
  }
}

// ---- pooling + final linear fused:
// out[c] += sum_{d in my slice} W[c,d] * sum_{n in blk} w[n]*V[n,d]
// softmax is near-one-hot: cold blocks (all w<1e-12) exit before touching V/W;
// skipped terms contribute < 1.6e-7 total.
__global__ __launch_bounds__(256) void k_pool(const float* __restrict__ V,
                                              const float* __restrict__ s,
                                              const float* __restrict__ stats,
                                              const float* __restrict__ W,
                                              float* __restrict__ out) {
  __shared__ float wsm[128];
  __shared__ int hot;
  __shared__ float sred[4][NCLS];
  const int tid = threadIdx.x;
  if (tid == 0) hot = 0;
  __syncthreads();
  const float mx = stats[0], inv = stats[1];
  const int n0 = blockIdx.x * 128;
  if (tid < 128) {
    const float w = __expf(s[n0 + tid] - mx) * inv;
    wsm[tid] = w;
    if (w > 1e-12f) atomicOr(&hot, 1);
  }
  __syncthreads();
  if (hot == 0) return;

  float acc[8] = {0.f, 0.f, 0.f, 0.f, 0.f, 0.f, 0.f, 0.f};
  for (int r = 0; r < 128; ++r) {
    const float w = wsm[r];     // block-uniform branch
    if (w > 1e-12f) {
      const float4* vp = (const float4*)&V[(size_t)(n0 + r) * DIM + tid * 8];
      float4 va = vp[0], vb = vp[1];
      acc[0] += w * va.x; acc[1] += w * va.y; acc[2] += w * va.z; acc[3] += w * va.w;
      acc[4] += w * vb.x; acc[5] += w * vb.y; acc[6] += w * vb.z; acc[7] += w * vb.w;
    }
  }
  // project onto W rows (final linear), block-reduce, one atomicAdd per class
  float pc[NCLS];
#pragma unroll
  for (int c = 0; c < NCLS; ++c) {
    const float4* w4 = (const float4*)&W[(size_t)c * DIM + tid * 8];
    const float4 wa = w4[0], wb = w4[1];
    pc[c] = wa.x * acc[0] + wa.y * acc[1] + wa.z * acc[2] + wa.w * acc[3] +
            wb.x * acc[4] + wb.y * acc[5] + wb.z * acc[6] + wb.w * acc[7];
  }
  const int lane = tid & 63, wvi = tid >> 6;
#pragma unroll
  for (int c = 0; c < NCLS; ++c)
    for (int o = 32; o > 0; o >>= 1) pc[c] += __shfl_xor(pc[c], o);
  if (lane == 0)
#pragma unroll
    for (int c = 0; c < NCLS; ++c) sred[wvi][c] = pc[c];
  __syncthreads();
  if (tid < NCLS)
    atomicAdd(&out[tid], sred[0][tid] + sred[1][tid] +
                         sred[2][tid] + sred[3][tid]);
}

extern "C" void kernel_launch(void* const* d_in, const int* in_sizes, int n_in,
                              void* d_out, int out_size, void* d_ws, size_t ws_size,
                              hipStream_t stream) {
  const float* Vp   = (const float*)d_in[0];  // [N, 2048]
  const float* Ut   = (const float*)d_in[1];  // [512, 2048]
  const float* Wmta = (const float*)d_in[2];  // [1, 512]
  const float* W    = (const float*)d_in[3];  // [4, 2048]
  float* out = (float*)d_out;

  char* ws = (char*)d_ws;
  _Float16* Uhi  = (_Float16*)(ws + OFF_UHI);
  float*    sBuf = (float*)(ws + OFF_S);
  float*    stat = (float*)(ws + OFF_STAT);

  // 4 dispatches total (memsets fused into k_cvt/k_stats)
  k_cvt<<<(DP * DIM / 8) / 256, 256, 0, stream>>>((const float4*)Ut,
                                                  (half8_t*)Uhi,
                                                  (float4*)sBuf);
  k_score_gemm<<<(DP / 256) * (N_INST / 256), 512, 0, stream>>>(Uhi, Vp, Wmta, sBuf);
  k_stats<<<1, 1024, 0, stream>>>(sBuf, stat, out);
  k_pool<<<N_INST / 128, 256, 0, stream>>>(Vp, sBuf, stat, W, out);
}